// Round 3
// baseline (310.663 us; speedup 1.0000x reference)
//
#include <hip/hip_runtime.h>
#include <stdint.h>

#define Bn 4
#define An 3
#define Hn 168
#define Wn 256
#define Mn 32
#define HWn (Hn*Wn)
#define Nn (HWn*An)          // 129024
#define POS_CAP 8192
#define TIE_CAP 49152        // deferred tie-anchors per image (~13K expected)
#define NPERIM 256
#define NPOSMAX 128
#define FG_THR 0.7f
#define BG_THR 0.3f
#define BETA (1.0f/9.0f)

#define NBLK 126             // blocks per image
#define APT 4                // anchors/thread
#define STRIDE (NBLK * 256)  // 32256
#define NWAVES (NBLK * 4)    // 504 waves per image
#define BUCKET_CAP 256       // per-bin bucket (expected ~57/bin)

// ---- workspace layout (uint32 word offsets) ----
// [0, ZERO_WORDS) is zeroed by k0 each iteration.
#define OFF_POSCNT 0            // Bn
#define OFF_TIECNT 4            // Bn
#define OFF_COUNT  8            // 1
#define OFF_CLS    9            // 1 (float bits)
#define OFF_REG    10           // 1 (float bits)
#define OFF_DONE   11           // 1
#define OFF_BINCNT 16           // Bn*1024 = 4096              -> 4112
#define OFF_BINBCE 4112         // Bn*1024 = 4096              -> 8208 (float bits)
#define ZERO_WORDS 8208
#define OFF_WPCM   8208         // Bn*NWAVES*32 = 64512        -> 72720 (wave colmax bits)
#define OFF_PLIST  72720        // Bn*POS_CAP*2 = 65536        -> 138256
#define OFF_BUCKET 138256       // Bn*1024*BUCKET_CAP*2 = 2097152 -> 2235408
#define OFF_TIE    2235408      // Bn*TIE_CAP*4 = 786432       -> 3021840 (~12.1MB)

// ------------------- threefry2x32 (20 rounds) -------------------
__device__ __forceinline__ uint32_t rotl32(uint32_t v, int n) { return (v << n) | (v >> (32 - n)); }

__device__ __forceinline__ void tf2x32(uint32_t k0, uint32_t k1, uint32_t x0, uint32_t x1,
                                       uint32_t& o0, uint32_t& o1) {
    uint32_t k2 = k0 ^ k1 ^ 0x1BD11BDAu;
    x0 += k0; x1 += k1;
    x0 += x1; x1 = rotl32(x1, 13); x1 ^= x0;
    x0 += x1; x1 = rotl32(x1, 15); x1 ^= x0;
    x0 += x1; x1 = rotl32(x1, 26); x1 ^= x0;
    x0 += x1; x1 = rotl32(x1, 6);  x1 ^= x0;
    x0 += k1; x1 += k2 + 1u;
    x0 += x1; x1 = rotl32(x1, 17); x1 ^= x0;
    x0 += x1; x1 = rotl32(x1, 29); x1 ^= x0;
    x0 += x1; x1 = rotl32(x1, 16); x1 ^= x0;
    x0 += x1; x1 = rotl32(x1, 24); x1 ^= x0;
    x0 += k2; x1 += k0 + 2u;
    x0 += x1; x1 = rotl32(x1, 13); x1 ^= x0;
    x0 += x1; x1 = rotl32(x1, 15); x1 ^= x0;
    x0 += x1; x1 = rotl32(x1, 26); x1 ^= x0;
    x0 += x1; x1 = rotl32(x1, 6);  x1 ^= x0;
    x0 += k0; x1 += k1 + 3u;
    x0 += x1; x1 = rotl32(x1, 17); x1 ^= x0;
    x0 += x1; x1 = rotl32(x1, 29); x1 ^= x0;
    x0 += x1; x1 = rotl32(x1, 16); x1 ^= x0;
    x0 += x1; x1 = rotl32(x1, 24); x1 ^= x0;
    x0 += k1; x1 += k2 + 4u;
    x0 += x1; x1 = rotl32(x1, 13); x1 ^= x0;
    x0 += x1; x1 = rotl32(x1, 15); x1 ^= x0;
    x0 += x1; x1 = rotl32(x1, 26); x1 ^= x0;
    x0 += x1; x1 = rotl32(x1, 6);  x1 ^= x0;
    x0 += k2; x1 += k0 + 5u;
    o0 = x0; o1 = x1;
}

__device__ __forceinline__ uint32_t rng_m23(uint32_t k0, uint32_t k1, uint32_t i) {
    uint32_t o0, o1;
    tf2x32(k0, k1, 0u, i, o0, o1);
    return (o0 ^ o1) >> 9;
}

// volatile load (bypass any stale L1 line; belt-and-braces for same-kernel RMW readback)
__device__ __forceinline__ uint32_t vload(const uint32_t* p) {
    return *(const volatile uint32_t*)p;
}

// ------------------- IoU (single definition) ------------
__device__ __forceinline__ float iou_one(float a0, float a1, float a2, float a3,
                                         float t0, float t1, float t2, float t3) {
    float xtl = fmaxf(a0, t0), ytl = fmaxf(a1, t1);
    float xrb = fminf(a2, t2), yrb = fminf(a3, t3);
    float iw = fmaxf(xrb - xtl + 1.0f, 0.0f);
    float ih = fmaxf(yrb - ytl + 1.0f, 0.0f);
    float inter = iw * ih;
    float area1 = (a2 - a0 + 1.0f) * (a3 - a1 + 1.0f);
    float area2 = (t2 - t0 + 1.0f) * (t3 - t1 + 1.0f);
    return inter * __builtin_amdgcn_rcpf(area1 + area2 - inter);
}

__device__ __forceinline__ float bce0(float l) {   // BCE(l, target=0)
    return fmaxf(l, 0.0f) + log1pf(expf(-fabsf(l)));
}

// ------------------- selection order (JAX top_k: larger priority first, tie -> smaller idx)
__device__ __forceinline__ bool sel_less(uint2 a, uint2 b) {
    return (a.x > b.x) || (a.x == b.x && a.y < b.y);
}

__device__ void bitonic_sort_shared(uint2* buf, int n) {   // n = pow2
    for (int k = 2; k <= n; k <<= 1) {
        for (int j = k >> 1; j > 0; j >>= 1) {
            for (int t = (int)threadIdx.x; t < n; t += 256) {
                int ixj = t ^ j;
                if (ixj > t) {
                    uint2 x = buf[t], y = buf[ixj];
                    bool up = ((t & k) == 0);
                    bool sw = up ? sel_less(y, x) : sel_less(x, y);
                    if (sw) { buf[t] = y; buf[ixj] = x; }
                }
            }
            __syncthreads();
        }
    }
}

// =====================================================================================
// K0: zero control words + bin counters/sums (k1 atomics need pre-zeroed state).
// =====================================================================================
__global__ void __launch_bounds__(256) k0_init(uint32_t* __restrict__ ws) {
    int i = blockIdx.x * 256 + (int)threadIdx.x;
    if (i < ZERO_WORDS) ws[i] = 0u;
}

// =====================================================================================
// K1: IoU pass + FULL categorize for unambiguous anchors.
//  - FG positives -> PLIST (wave-aggregated ticket)
//  - certain negatives (bg, tie==0) -> bins/buckets + immediate BCE
//  - ambiguous (inside, !fg, tie!=0, ~12%) -> deferred TIE list for k3
// restore resolution (k3): iou==global_cm <=> iou==wave_cm AND wave_cm==global_cm
// (exact: identical fmaxf chains; validated rounds 1-2, absmax 0.0).
// =====================================================================================
__global__ void __launch_bounds__(256) k1_iou(const float* __restrict__ anchors,
                                              const float* __restrict__ targets,
                                              const float* __restrict__ sizes,
                                              const float* __restrict__ logits,
                                              uint32_t* __restrict__ ws) {
    const int b = blockIdx.y, j = blockIdx.x, tid = threadIdx.x;
    const int wid = tid >> 6, lane = tid & 63;

    uint32_t key0, key1;
    tf2x32(0u, 42u, 0u, (uint32_t)b, key0, key1);   // per-image RNG key (pure fn, inline)

    const int base = j * 256 + tid;
    float4 av[APT];
    #pragma unroll
    for (int k = 0; k < APT; ++k)
        av[k] = ((const float4*)anchors)[b * Nn + base + k * STRIDE];

    float rowmax[APT]; int ori[APT]; uint32_t tie[APT];
    #pragma unroll
    for (int k = 0; k < APT; ++k) { rowmax[k] = -1.0f; ori[k] = 0; tie[k] = 0u; }

    float mycm = 0.0f;   // lane t (t<32) ends holding wave colmax of target t
    #pragma unroll 4
    for (int t = 0; t < Mn; ++t) {
        float4 tv = ((const float4*)targets)[b * Mn + t];
        float io[APT];
        float m0 = 0.0f;
        #pragma unroll
        for (int k = 0; k < APT; ++k) {
            io[k] = iou_one(av[k].x, av[k].y, av[k].z, av[k].w, tv.x, tv.y, tv.z, tv.w);
            if (io[k] > rowmax[k]) { rowmax[k] = io[k]; ori[k] = t; }
            m0 = fmaxf(m0, io[k]);
        }
        #pragma unroll
        for (int o = 32; o > 0; o >>= 1) m0 = fmaxf(m0, __shfl_xor(m0, o, 64));
        if (lane == t) mycm = m0;
        #pragma unroll
        for (int k = 0; k < APT; ++k)
            tie[k] |= (io[k] == m0) ? (1u << t) : 0u;
    }

    // wave colmax -> global (coalesced; one store per lane<32)
    if (lane < Mn)
        ws[OFF_WPCM + ((size_t)b * NWAVES + (j * 4 + wid)) * 32 + lane] = __float_as_uint(mycm);

    const float sh = sizes[b * 2 + 0], sw = sizes[b * 2 + 1];
    unsigned long long lt_mask = (lane == 63) ? 0x7FFFFFFFFFFFFFFFull
                                              : ((1ull << lane) - 1ull);
    #pragma unroll
    for (int k = 0; k < APT; ++k) {
        const int i = base + k * STRIDE;
        bool inside = (av[k].x >= 0.0f) && (av[k].y >= 0.0f) &&
                      (av[k].z <= sw - 1.0f) && (av[k].w <= sh - 1.0f);
        bool fg = rowmax[k] >= FG_THR;
        bool bg = rowmax[k] < BG_THR;
        bool posn  = inside && fg;                       // positive regardless of restore
        bool defern = inside && !fg && (tie[k] != 0u);   // restore could flip to positive
        bool negn  = inside && bg && (tie[k] == 0u);     // certain negative
        uint32_t m = rng_m23(key0, key1, (uint32_t)i);

        unsigned long long pmask = __ballot(posn);
        if (pmask) {
            int leader = __ffsll((long long)pmask) - 1;
            uint32_t bb = 0;
            if (lane == leader) bb = atomicAdd(&ws[OFF_POSCNT + b], (uint32_t)__popcll(pmask));
            bb = __shfl(bb, leader, 64);
            if (posn) {
                uint32_t p = bb + (uint32_t)__popcll(pmask & lt_mask);
                if (p < POS_CAP)
                    ((uint2*)(ws + OFF_PLIST))[(size_t)b * POS_CAP + p] =
                        make_uint2(m, (uint32_t)i | ((uint32_t)ori[k] << 17));
            }
        }
        unsigned long long dmask = __ballot(defern);
        if (dmask) {
            int leader = __ffsll((long long)dmask) - 1;
            uint32_t bb = 0;
            if (lane == leader) bb = atomicAdd(&ws[OFF_TIECNT + b], (uint32_t)__popcll(dmask));
            bb = __shfl(bb, leader, 64);
            if (defern) {
                uint32_t p = bb + (uint32_t)__popcll(dmask & lt_mask);
                if (p < TIE_CAP)
                    ((uint4*)(ws + OFF_TIE))[(size_t)b * TIE_CAP + p] =
                        make_uint4(tie[k], m,
                                   (uint32_t)i | ((uint32_t)ori[k] << 17) | (bg ? (1u << 22) : 0u),
                                   0u);
            }
        }
        if (negn) {
            int bin = (int)(m >> 13);
            uint32_t slot = atomicAdd(&ws[OFF_BINCNT + (b << 10) + bin], 1u);
            if (slot < BUCKET_CAP)
                ((uint2*)(ws + OFF_BUCKET))[((((size_t)b << 10) + bin) << 8) + slot] =
                    make_uint2(m, (uint32_t)i);
            int a = i % An, hw = i / An;
            float l = logits[(b * An + a) * HWn + hw];
            atomicAdd((float*)&ws[OFF_BINBCE + (b << 10) + bin], bce0(l));
        }
    }
}

// =====================================================================================
// K3: per-image finalize (one block per image).
//  A) global colmax from WPCM   B) eqmask per k1-wave   C) resolve deferred tie-anchors
//  D) bin suffix-scan -> boundary, BCE of included bins  E) positives sort + reg loss
// =====================================================================================
__global__ void __launch_bounds__(256) k3_final(const float* __restrict__ anchors,
                                                const float* __restrict__ targets,
                                                const float* __restrict__ logits,
                                                const float* __restrict__ bregs,
                                                uint32_t* __restrict__ ws,
                                                float* __restrict__ out) {
    const int b = blockIdx.x, tid = threadIdx.x;
    __shared__ uint32_t cmbits[Mn];
    __shared__ float redf[256];
    __shared__ uint32_t eq[512];          // eqmask per k1-wave (NWAVES=504)
    __shared__ float lbce[1024];          // late-negative BCE per bin
    __shared__ union { uint32_t csum[256]; uint2 buf[2048]; } sh;
    __shared__ float red[256];
    __shared__ int s_bd, s_need;
    float cls = 0.0f, reg = 0.0f;

    // ---- A: global colmax (exact: max assoc/comm over identical chains) ----
    {
        int t = tid & 31, sub = tid >> 5;
        float acc = 0.0f;
        for (int w = sub; w < NWAVES; w += 8)
            acc = fmaxf(acc, __uint_as_float(ws[OFF_WPCM + ((size_t)b * NWAVES + w) * 32 + t]));
        redf[tid] = acc;
        __syncthreads();
        if (sub == 0) {
            #pragma unroll
            for (int q = 1; q < 8; ++q) acc = fmaxf(acc, redf[t + 32 * q]);
            cmbits[t] = __float_as_uint(acc);
        }
    }
    for (int q = tid; q < 1024; q += 256) lbce[q] = 0.0f;
    __syncthreads();

    // ---- B: eqmask per wave ----
    for (int w = tid; w < NWAVES; w += 256) {
        const uint32_t* wp = ws + OFF_WPCM + ((size_t)b * NWAVES + w) * 32;
        uint32_t e = 0;
        #pragma unroll 8
        for (int t2 = 0; t2 < Mn; ++t2)
            e |= (wp[t2] == cmbits[t2]) ? (1u << t2) : 0u;
        eq[w] = e;
    }
    __syncthreads();

    // ---- C: resolve deferred tie-anchors ----
    {
        uint32_t tcu = vload(ws + OFF_TIECNT + b);
        int tcnt = (tcu < (uint32_t)TIE_CAP) ? (int)tcu : TIE_CAP;
        const uint4* tlist = (const uint4*)(ws + OFF_TIE) + (size_t)b * TIE_CAP;
        for (int idx = tid; idx < tcnt; idx += 256) {
            uint4 e = tlist[idx];
            int i = (int)(e.z & 0x1FFFFu);
            int w = (i % STRIDE) >> 6;              // originating k1 wave
            if (e.x & eq[w]) {                       // restored -> positive
                uint32_t p = atomicAdd(&ws[OFF_POSCNT + b], 1u);
                if (p < POS_CAP)
                    ((uint2*)(ws + OFF_PLIST))[(size_t)b * POS_CAP + p] =
                        make_uint2(e.y, e.z & 0x3FFFFFu);   // strip bg bit
            } else if (e.z & (1u << 22)) {           // bg, not restored -> negative
                uint32_t m = e.y;
                int bin = (int)(m >> 13);
                uint32_t slot = atomicAdd(&ws[OFF_BINCNT + (b << 10) + bin], 1u);
                if (slot < BUCKET_CAP)
                    ((uint2*)(ws + OFF_BUCKET))[((((size_t)b << 10) + bin) << 8) + slot] =
                        make_uint2(m, (uint32_t)i);
                int a = i % An, hw = i / An;
                float l = logits[(b * An + a) * HWn + hw];
                atomicAdd(&lbce[bin], bce0(l));
            }
            // mid, not restored -> dropped
        }
    }
    __syncthreads();

    // ---- D: bin suffix scan -> boundary ----
    uint32_t c4[4];
    #pragma unroll
    for (int q = 0; q < 4; ++q) c4[q] = vload(ws + OFF_BINCNT + (b << 10) + 4 * tid + q);
    uint32_t sum = c4[0] + c4[1] + c4[2] + c4[3];
    sh.csum[tid] = sum;
    __syncthreads();
    for (int off = 1; off < 256; off <<= 1) {
        uint32_t mine = sh.csum[tid];
        uint32_t add = (tid + off < 256) ? sh.csum[tid + off] : 0u;
        __syncthreads();
        sh.csum[tid] = mine + add;
        __syncthreads();
    }
    uint32_t pc = vload(ws + OFF_POSCNT + b);        // final (incl. restored)
    int num_pos = (pc < (uint32_t)NPOSMAX) ? (int)pc : NPOSMAX;
    int k_neg = NPERIM - num_pos;
    uint32_t total = sh.csum[0];
    if ((int)total < k_neg) {
        if (tid == 0) { s_bd = -1; s_need = 0; }
    } else {
        uint32_t incl = sh.csum[tid];
        uint32_t next = (tid < 255) ? sh.csum[tid + 1] : 0u;
        if ((int)incl >= k_neg && (int)next < k_neg) {
            int cum = (int)next;
            int boundary = -1, needed = 0;
            #pragma unroll
            for (int q = 3; q >= 0; --q) {
                int c = (int)c4[q];
                if (cum + c >= k_neg) { boundary = 4 * tid + q; needed = k_neg - cum; break; }
                cum += c;
            }
            s_bd = boundary; s_need = needed;
        }
    }
    if (tid == 0) {
        int sel_negs = ((int)total < k_neg) ? (int)total : k_neg;
        atomicAdd(&ws[OFF_COUNT], (uint32_t)(num_pos + sel_negs));
    }
    __syncthreads();
    const int bd = s_bd, need = s_need;

    // fully-included bins: per-bin BCE sums (k1 global + k3 late LDS)
    #pragma unroll
    for (int q = 0; q < 4; ++q) {
        int bin = 4 * tid + q;
        if (bin > bd) {
            float gb = __uint_as_float(vload(ws + OFF_BINBCE + (b << 10) + bin));
            cls += gb + lbce[bin];
        }
    }
    __syncthreads();   // csum dead; buf reuse begins

    // boundary bin: sort entries, take top-`need`
    if (need > 0) {
        int cnt = (int)vload(ws + OFF_BINCNT + (b << 10) + bd);
        if (cnt > BUCKET_CAP) cnt = BUCKET_CAP;
        const uint2* bkt = (const uint2*)(ws + OFF_BUCKET) + ((((size_t)b << 10) + bd) << 8);
        for (int t = tid; t < cnt; t += 256) sh.buf[t] = bkt[t];
        int npad = 1; while (npad < cnt) npad <<= 1;
        for (int t = tid; t < npad; t += 256) if (t >= cnt) sh.buf[t] = make_uint2(0u, 0xFFFFFFFFu);
        __syncthreads();
        bitonic_sort_shared(sh.buf, npad);
        int sel = (need < cnt) ? need : cnt;
        for (int t = tid; t < sel; t += 256) {
            int i = (int)sh.buf[t].y;
            int a = i % An, hw = i / An;
            float l = logits[(b * An + a) * HWn + hw];
            cls += bce0(l);
        }
    }
    __syncthreads();

    // ---- E: positives ----
    {
        int pci = (pc < (uint32_t)POS_CAP) ? (int)pc : POS_CAP;
        const uint2* plist = (const uint2*)(ws + OFF_PLIST) + (size_t)b * POS_CAP;
        int psel = (pci < NPOSMAX) ? pci : NPOSMAX;
        bool use_buf = false;
        if (pci > NPOSMAX) {
            int n = (pci < 2048) ? pci : 2048;
            for (int t = tid; t < n; t += 256) sh.buf[t] = plist[t];
            int npad = 1; while (npad < n) npad <<= 1;
            for (int t = tid; t < npad; t += 256) if (t >= n) sh.buf[t] = make_uint2(0u, 0xFFFFFFFFu);
            __syncthreads();
            bitonic_sort_shared(sh.buf, npad);
            use_buf = true;
            psel = (NPOSMAX < n) ? NPOSMAX : n;
        }
        for (int t = tid; t < psel; t += 256) {
            uint32_t packed = use_buf ? sh.buf[t].y : plist[t].y;
            int i = (int)(packed & 0x1FFFFu);
            int orit = (int)(packed >> 17);
            int a = i % An, hw = i / An;
            float l = logits[(b * An + a) * HWn + hw];
            cls += fmaxf(l, 0.0f) - l + log1pf(expf(-fabsf(l)));   // BCE(l,1)
            float4 avx = ((const float4*)anchors)[b * Nn + i];
            float4 tv = ((const float4*)targets)[b * Mn + orit];
            float aws = avx.z - avx.x + 1.0f, ahs = avx.w - avx.y + 1.0f;
            float axc = avx.x + 0.5f * aws, ayc = avx.y + 0.5f * ahs;
            float tws = tv.z - tv.x + 1.0f, ths = tv.w - tv.y + 1.0f;
            float txc = tv.x + 0.5f * tws, tyc = tv.y + 0.5f * ths;
            float off0 = (txc - axc) / aws;
            float off1 = (tyc - ayc) / ahs;
            float off2 = logf(tws / aws);
            float off3 = logf(ths / ahs);
            float br0 = bregs[(b * 12 + a * 4 + 0) * HWn + hw];
            float br1 = bregs[(b * 12 + a * 4 + 1) * HWn + hw];
            float br2 = bregs[(b * 12 + a * 4 + 2) * HWn + hw];
            float br3 = bregs[(b * 12 + a * 4 + 3) * HWn + hw];
            float d;
            d = fabsf(br0 - off0); reg += (d < BETA) ? 0.5f * d * d / BETA : d - 0.5f * BETA;
            d = fabsf(br1 - off1); reg += (d < BETA) ? 0.5f * d * d / BETA : d - 0.5f * BETA;
            d = fabsf(br2 - off2); reg += (d < BETA) ? 0.5f * d * d / BETA : d - 0.5f * BETA;
            d = fabsf(br3 - off3); reg += (d < BETA) ? 0.5f * d * d / BETA : d - 0.5f * BETA;
        }
    }

    // ---- reductions + cross-image epilogue ----
    red[tid] = cls;
    __syncthreads();
    for (int s = 128; s > 0; s >>= 1) {
        if (tid < s) red[tid] += red[tid + s];
        __syncthreads();
    }
    if (tid == 0 && red[0] != 0.0f) atomicAdd((float*)&ws[OFF_CLS], red[0]);
    __syncthreads();
    red[tid] = reg;
    __syncthreads();
    for (int s = 128; s > 0; s >>= 1) {
        if (tid < s) red[tid] += red[tid + s];
        __syncthreads();
    }
    if (tid == 0) {
        if (red[0] != 0.0f) atomicAdd((float*)&ws[OFF_REG], red[0]);
        __threadfence();
        uint32_t old = atomicAdd(&ws[OFF_DONE], 1u);
        if (old == Bn - 1) {
            float cls_tot = __uint_as_float(atomicAdd(&ws[OFF_CLS], 0u));
            float reg_tot = __uint_as_float(atomicAdd(&ws[OFF_REG], 0u));
            float cnt = (float)atomicAdd(&ws[OFF_COUNT], 0u);
            out[0] = cls_tot / cnt;
            out[1] = reg_tot / cnt;
        }
    }
}

extern "C" void kernel_launch(void* const* d_in, const int* in_sizes, int n_in,
                              void* d_out, int out_size, void* d_ws, size_t ws_size,
                              hipStream_t stream) {
    const float* anchors = (const float*)d_in[0];   // [B, N, 4]
    const float* logits  = (const float*)d_in[1];   // [B, A, H, W]
    const float* bregs   = (const float*)d_in[2];   // [B, 4A, H, W]
    const float* sizes   = (const float*)d_in[3];   // [B, 2]
    const float* targets = (const float*)d_in[4];   // [B, M, 4]
    float* out = (float*)d_out;
    uint32_t* ws = (uint32_t*)d_ws;

    k0_init<<<dim3((ZERO_WORDS + 255) / 256), dim3(256), 0, stream>>>(ws);
    k1_iou<<<dim3(NBLK, Bn), dim3(256), 0, stream>>>(anchors, targets, sizes, logits, ws);
    k3_final<<<dim3(Bn), dim3(256), 0, stream>>>(anchors, targets, logits, bregs, ws, out);
}

// Round 4
// 181.351 us; speedup vs baseline: 1.7130x; 1.7130x over previous
//
#include <hip/hip_runtime.h>
#include <stdint.h>

#define Bn 4
#define An 3
#define Hn 168
#define Wn 256
#define Mn 32
#define HWn (Hn*Wn)
#define Nn (HWn*An)          // 129024
#define POS_CAP 8192
#define NPERIM 256
#define NPOSMAX 128
#define FG_THR 0.7f
#define BG_THR 0.3f
#define BETA (1.0f/9.0f)

#define NBLK 126             // blocks per image
#define APT 4                // anchors/thread
#define STRIDE (NBLK * 256)  // 32256
#define NWAVES (NBLK * 4)    // 504 waves per image
#define BUCKET_CAP 256       // per-bin bucket (avg ~78/bin, Poisson tail safe)
#define TSEG_CAP 256         // per-wave deferred segment (max possible = 4*64 = 256)

// ---- workspace layout (uint32 word offsets) ----
// [0, ZERO_WORDS) zeroed by k0 each iteration.
#define OFF_POSCNT 0            // Bn
#define OFF_COUNT  8            // 1
#define OFF_CLS    9            // 1 (float bits)
#define OFF_REG    10           // 1 (float bits)
#define OFF_DONE   11           // 1
#define OFF_BINCNT 16           // Bn*1024 = 4096               -> 4112
#define OFF_BINBCE 4112         // Bn*1024 = 4096               -> 8208 (float bits)
#define ZERO_WORDS 8208
#define OFF_WPCM   8208         // Bn*NWAVES*32 = 64512         -> 72720 (wave colmax bits)
#define OFF_TSEGC  72720        // Bn*NWAVES = 2016             -> 74736 (per-wave defer counts)
#define OFF_PLIST  74736        // Bn*POS_CAP*2 = 65536         -> 140272
#define OFF_BUCKET 140272       // Bn*1024*BUCKET_CAP*2 = 2097152 -> 2237424
#define OFF_TSEG   2237424      // Bn*NWAVES*TSEG_CAP*4 = 2064384 -> 4301808 (~17.2MB)

// ------------------- threefry2x32 (20 rounds) -------------------
__device__ __forceinline__ uint32_t rotl32(uint32_t v, int n) { return (v << n) | (v >> (32 - n)); }

__device__ __forceinline__ void tf2x32(uint32_t k0, uint32_t k1, uint32_t x0, uint32_t x1,
                                       uint32_t& o0, uint32_t& o1) {
    uint32_t k2 = k0 ^ k1 ^ 0x1BD11BDAu;
    x0 += k0; x1 += k1;
    x0 += x1; x1 = rotl32(x1, 13); x1 ^= x0;
    x0 += x1; x1 = rotl32(x1, 15); x1 ^= x0;
    x0 += x1; x1 = rotl32(x1, 26); x1 ^= x0;
    x0 += x1; x1 = rotl32(x1, 6);  x1 ^= x0;
    x0 += k1; x1 += k2 + 1u;
    x0 += x1; x1 = rotl32(x1, 17); x1 ^= x0;
    x0 += x1; x1 = rotl32(x1, 29); x1 ^= x0;
    x0 += x1; x1 = rotl32(x1, 16); x1 ^= x0;
    x0 += x1; x1 = rotl32(x1, 24); x1 ^= x0;
    x0 += k2; x1 += k0 + 2u;
    x0 += x1; x1 = rotl32(x1, 13); x1 ^= x0;
    x0 += x1; x1 = rotl32(x1, 15); x1 ^= x0;
    x0 += x1; x1 = rotl32(x1, 26); x1 ^= x0;
    x0 += x1; x1 = rotl32(x1, 6);  x1 ^= x0;
    x0 += k0; x1 += k1 + 3u;
    x0 += x1; x1 = rotl32(x1, 17); x1 ^= x0;
    x0 += x1; x1 = rotl32(x1, 29); x1 ^= x0;
    x0 += x1; x1 = rotl32(x1, 16); x1 ^= x0;
    x0 += x1; x1 = rotl32(x1, 24); x1 ^= x0;
    x0 += k1; x1 += k2 + 4u;
    x0 += x1; x1 = rotl32(x1, 13); x1 ^= x0;
    x0 += x1; x1 = rotl32(x1, 15); x1 ^= x0;
    x0 += x1; x1 = rotl32(x1, 26); x1 ^= x0;
    x0 += x1; x1 = rotl32(x1, 6);  x1 ^= x0;
    x0 += k2; x1 += k0 + 5u;
    o0 = x0; o1 = x1;
}

__device__ __forceinline__ uint32_t rng_m23(uint32_t k0, uint32_t k1, uint32_t i) {
    uint32_t o0, o1;
    tf2x32(k0, k1, 0u, i, o0, o1);
    return (o0 ^ o1) >> 9;
}

// volatile load: bypass L1 for values updated by atomics earlier in the same kernel
__device__ __forceinline__ uint32_t vload(const uint32_t* p) {
    return *(const volatile uint32_t*)p;
}

// ------------------- IoU (single definition) ------------
__device__ __forceinline__ float iou_one(float a0, float a1, float a2, float a3,
                                         float t0, float t1, float t2, float t3) {
    float xtl = fmaxf(a0, t0), ytl = fmaxf(a1, t1);
    float xrb = fminf(a2, t2), yrb = fminf(a3, t3);
    float iw = fmaxf(xrb - xtl + 1.0f, 0.0f);
    float ih = fmaxf(yrb - ytl + 1.0f, 0.0f);
    float inter = iw * ih;
    float area1 = (a2 - a0 + 1.0f) * (a3 - a1 + 1.0f);
    float area2 = (t2 - t0 + 1.0f) * (t3 - t1 + 1.0f);
    return inter * __builtin_amdgcn_rcpf(area1 + area2 - inter);
}

__device__ __forceinline__ float bce0(float l) {   // BCE(l, target=0)
    return fmaxf(l, 0.0f) + log1pf(expf(-fabsf(l)));
}

// ------------------- selection order (JAX top_k: larger priority first, tie -> smaller idx)
__device__ __forceinline__ bool sel_less(uint2 a, uint2 b) {
    return (a.x > b.x) || (a.x == b.x && a.y < b.y);
}

__device__ void bitonic_sort_shared(uint2* buf, int n) {   // n = pow2
    for (int k = 2; k <= n; k <<= 1) {
        for (int j = k >> 1; j > 0; j >>= 1) {
            for (int t = (int)threadIdx.x; t < n; t += (int)blockDim.x) {
                int ixj = t ^ j;
                if (ixj > t) {
                    uint2 x = buf[t], y = buf[ixj];
                    bool up = ((t & k) == 0);
                    bool sw = up ? sel_less(y, x) : sel_less(x, y);
                    if (sw) { buf[t] = y; buf[ixj] = x; }
                }
            }
            __syncthreads();
        }
    }
}

// =====================================================================================
// K0: zero control words + bin counters/sums.
// =====================================================================================
__global__ void __launch_bounds__(256) k0_init(uint32_t* __restrict__ ws) {
    int i = blockIdx.x * 256 + (int)threadIdx.x;
    if (i < ZERO_WORDS) ws[i] = 0u;
}

// =====================================================================================
// K1: IoU pass + full categorize for unambiguous anchors.
//  - FG positives -> PLIST (wave-aggregated ticket; rare)
//  - certain negatives (bg, tie==0) -> bins/buckets + immediate BCE (per-lane scattered
//    atomics over 4096 addresses; proven fast in R2)
//  - ambiguous (inside, !fg, tie!=0) -> PER-WAVE private segment, ZERO atomics.
//    (R3's global TIECNT ticket = ~8K serialized same-address RMW/image = 126us. Never
//     put a per-wave-frequency ticket on one address.)
// =====================================================================================
__global__ void __launch_bounds__(256) k1_iou(const float* __restrict__ anchors,
                                              const float* __restrict__ targets,
                                              const float* __restrict__ sizes,
                                              const float* __restrict__ logits,
                                              uint32_t* __restrict__ ws) {
    const int b = blockIdx.y, j = blockIdx.x, tid = threadIdx.x;
    const int wid = tid >> 6, lane = tid & 63;

    uint32_t key0, key1;
    tf2x32(0u, 42u, 0u, (uint32_t)b, key0, key1);   // per-image RNG key (pure fn)

    const int base = j * 256 + tid;
    float4 av[APT];
    #pragma unroll
    for (int k = 0; k < APT; ++k)
        av[k] = ((const float4*)anchors)[b * Nn + base + k * STRIDE];

    float rowmax[APT]; int ori[APT]; uint32_t tie[APT];
    #pragma unroll
    for (int k = 0; k < APT; ++k) { rowmax[k] = -1.0f; ori[k] = 0; tie[k] = 0u; }

    float mycm = 0.0f;   // lane t (t<32) ends holding wave colmax of target t
    #pragma unroll 4
    for (int t = 0; t < Mn; ++t) {
        float4 tv = ((const float4*)targets)[b * Mn + t];
        float io[APT];
        float m0 = 0.0f;
        #pragma unroll
        for (int k = 0; k < APT; ++k) {
            io[k] = iou_one(av[k].x, av[k].y, av[k].z, av[k].w, tv.x, tv.y, tv.z, tv.w);
            if (io[k] > rowmax[k]) { rowmax[k] = io[k]; ori[k] = t; }
            m0 = fmaxf(m0, io[k]);
        }
        #pragma unroll
        for (int o = 32; o > 0; o >>= 1) m0 = fmaxf(m0, __shfl_xor(m0, o, 64));
        if (lane == t) mycm = m0;
        #pragma unroll
        for (int k = 0; k < APT; ++k)
            tie[k] |= (io[k] == m0) ? (1u << t) : 0u;
    }

    // wave colmax -> global (coalesced; one store per lane<32)
    const int wimg = j * 4 + wid;
    if (lane < Mn)
        ws[OFF_WPCM + ((size_t)b * NWAVES + wimg) * 32 + lane] = __float_as_uint(mycm);

    const float sh = sizes[b * 2 + 0], sw = sizes[b * 2 + 1];
    unsigned long long lt_mask = (lane == 63) ? 0x7FFFFFFFFFFFFFFFull
                                              : ((1ull << lane) - 1ull);
    uint4* tseg = (uint4*)(ws + OFF_TSEG) + ((size_t)b * NWAVES + wimg) * TSEG_CAP;
    uint32_t wcnt = 0;   // wave-uniform running defer count (from ballot popc)
    #pragma unroll
    for (int k = 0; k < APT; ++k) {
        const int i = base + k * STRIDE;
        bool inside = (av[k].x >= 0.0f) && (av[k].y >= 0.0f) &&
                      (av[k].z <= sw - 1.0f) && (av[k].w <= sh - 1.0f);
        bool fg = rowmax[k] >= FG_THR;
        bool bg = rowmax[k] < BG_THR;
        bool posn   = inside && fg;                      // positive regardless of restore
        bool defern = inside && !fg && (tie[k] != 0u);   // restore could flip to positive
        bool negn   = inside && bg && (tie[k] == 0u);    // certain negative
        uint32_t m = rng_m23(key0, key1, (uint32_t)i);

        unsigned long long pmask = __ballot(posn);
        if (pmask) {
            int leader = __ffsll((long long)pmask) - 1;
            uint32_t bb = 0;
            if (lane == leader) bb = atomicAdd(&ws[OFF_POSCNT + b], (uint32_t)__popcll(pmask));
            bb = __shfl(bb, leader, 64);
            if (posn) {
                uint32_t p = bb + (uint32_t)__popcll(pmask & lt_mask);
                if (p < POS_CAP)
                    ((uint2*)(ws + OFF_PLIST))[(size_t)b * POS_CAP + p] =
                        make_uint2(m, (uint32_t)i | ((uint32_t)ori[k] << 17));
            }
        }
        // deferred ties: ballot-compacted into the wave's private segment (no atomics)
        unsigned long long dmask = __ballot(defern);
        if (defern) {
            uint32_t slot = wcnt + (uint32_t)__popcll(dmask & lt_mask);
            tseg[slot] = make_uint4(tie[k], m,
                                    (uint32_t)i | ((uint32_t)ori[k] << 17) | (bg ? (1u << 22) : 0u),
                                    0u);
        }
        wcnt += (uint32_t)__popcll(dmask);
        // certain negatives: scattered per-lane atomics (4096 addresses; R2-proven)
        if (negn) {
            int bin = (int)(m >> 13);
            uint32_t slot = atomicAdd(&ws[OFF_BINCNT + (b << 10) + bin], 1u);
            if (slot < BUCKET_CAP)
                ((uint2*)(ws + OFF_BUCKET))[((((size_t)b << 10) + bin) << 8) + slot] =
                    make_uint2(m, (uint32_t)i);
            int a = i % An, hw = i / An;
            float l = logits[(b * An + a) * HWn + hw];
            atomicAdd((float*)&ws[OFF_BINBCE + (b << 10) + bin], bce0(l));
        }
    }
    if (lane == 0) ws[OFF_TSEGC + b * NWAVES + wimg] = wcnt;
}

// =====================================================================================
// K3: per-image finalize, 1024 threads (one block per image).
//  A) global colmax  B) eqmask/wave + segment-count scan  C) resolve deferred ties
//  D) per-bin suffix scan (1024<->1024) -> boundary + included-bin BCE
//  E) boundary-bin sort + positives epilogue + cross-image output
// =====================================================================================
__global__ void __launch_bounds__(1024) k3_final(const float* __restrict__ anchors,
                                                 const float* __restrict__ targets,
                                                 const float* __restrict__ logits,
                                                 const float* __restrict__ bregs,
                                                 uint32_t* __restrict__ ws,
                                                 float* __restrict__ out) {
    const int b = blockIdx.x, tid = threadIdx.x;
    __shared__ uint32_t cmbits[Mn];
    __shared__ float fred[1024];
    __shared__ uint32_t eq[512];       // eqmask per wave (NWAVES=504)
    __shared__ uint32_t incl[512];     // inclusive scan of per-wave defer counts
    __shared__ uint32_t csum[1024];    // per-bin suffix scan
    __shared__ uint2 buf[2048];
    __shared__ int s_bd, s_need;
    float cls = 0.0f, reg = 0.0f;

    // ---- A: global colmax (exact: max assoc/comm over identical fmaxf chains) ----
    {
        int t = tid & 31, sub = tid >> 5;   // 32 sub-groups
        float acc = 0.0f;
        for (int w = sub; w < NWAVES; w += 32)
            acc = fmaxf(acc, __uint_as_float(ws[OFF_WPCM + ((size_t)b * NWAVES + w) * 32 + t]));
        fred[tid] = acc;
        __syncthreads();
        if (sub == 0) {
            #pragma unroll
            for (int q = 1; q < 32; ++q) acc = fmaxf(acc, fred[t + 32 * q]);
            cmbits[t] = __float_as_uint(acc);
        }
    }
    __syncthreads();

    // ---- B: eqmask per wave + load defer counts ----
    if (tid < NWAVES) {
        const uint32_t* wp = ws + OFF_WPCM + ((size_t)b * NWAVES + tid) * 32;
        uint32_t e = 0;
        #pragma unroll 8
        for (int t2 = 0; t2 < Mn; ++t2)
            e |= (wp[t2] == cmbits[t2]) ? (1u << t2) : 0u;
        eq[tid] = e;
    }
    if (tid < 512) incl[tid] = (tid < NWAVES) ? ws[OFF_TSEGC + b * NWAVES + tid] : 0u;
    __syncthreads();
    for (int off = 1; off < 512; off <<= 1) {   // inclusive scan (Hillis-Steele)
        uint32_t v = 0;
        if (tid < 512) { v = incl[tid]; if (tid >= off) v += incl[tid - off]; }
        __syncthreads();
        if (tid < 512) incl[tid] = v;
        __syncthreads();
    }
    const int ttotal = (int)incl[511];

    // ---- C: resolve deferred ties (flat index + binary search over segments) ----
    for (int f = tid; f < ttotal; f += 1024) {
        int lo = 0, hi = 511;
        while (lo < hi) { int mid = (lo + hi) >> 1; if ((int)incl[mid] > f) hi = mid; else lo = mid + 1; }
        const int w = lo;
        const int o = f - ((w > 0) ? (int)incl[w - 1] : 0);
        uint4 e = ((const uint4*)(ws + OFF_TSEG))[((size_t)b * NWAVES + w) * TSEG_CAP + o];
        int i = (int)(e.z & 0x1FFFFu);
        if (e.x & eq[w]) {                       // restored -> positive
            uint32_t p = atomicAdd(&ws[OFF_POSCNT + b], 1u);
            if (p < POS_CAP)
                ((uint2*)(ws + OFF_PLIST))[(size_t)b * POS_CAP + p] =
                    make_uint2(e.y, e.z & 0x3FFFFFu);   // strip bg bit
        } else if (e.z & (1u << 22)) {           // bg, not restored -> negative
            uint32_t m = e.y;
            int bin = (int)(m >> 13);
            uint32_t slot = atomicAdd(&ws[OFF_BINCNT + (b << 10) + bin], 1u);
            if (slot < BUCKET_CAP)
                ((uint2*)(ws + OFF_BUCKET))[((((size_t)b << 10) + bin) << 8) + slot] =
                    make_uint2(m, (uint32_t)i);
            int a = i % An, hw = i / An;
            float l = logits[(b * An + a) * HWn + hw];
            atomicAdd((float*)&ws[OFF_BINBCE + (b << 10) + bin], bce0(l));
        }
        // mid, not restored -> dropped
    }
    __syncthreads();

    // ---- D: per-bin suffix scan (bin tid), boundary, included-bin BCE ----
    csum[tid] = vload(ws + OFF_BINCNT + (b << 10) + tid);
    __syncthreads();
    for (int off = 1; off < 1024; off <<= 1) {
        uint32_t v = csum[tid];
        uint32_t add = (tid + off < 1024) ? csum[tid + off] : 0u;
        __syncthreads();
        csum[tid] = v + add;
        __syncthreads();
    }
    uint32_t pc = vload(ws + OFF_POSCNT + b);    // final (incl. restored)
    int num_pos = (pc < (uint32_t)NPOSMAX) ? (int)pc : NPOSMAX;
    int k_neg = NPERIM - num_pos;
    uint32_t total = csum[0];
    if (tid == 0 && (int)total < k_neg) { s_bd = -1; s_need = 0; }
    {
        uint32_t inclv = csum[tid];
        uint32_t nxt = (tid < 1023) ? csum[tid + 1] : 0u;
        if ((int)total >= k_neg && (int)inclv >= k_neg && (int)nxt < k_neg) {
            s_bd = tid; s_need = k_neg - (int)nxt;
        }
    }
    if (tid == 0) {
        int sel_negs = ((int)total < k_neg) ? (int)total : k_neg;
        atomicAdd(&ws[OFF_COUNT], (uint32_t)(num_pos + sel_negs));
    }
    __syncthreads();
    const int bd = s_bd, need = s_need;
    if ((int)tid > bd)
        cls += __uint_as_float(vload(ws + OFF_BINBCE + (b << 10) + tid));
    __syncthreads();

    // ---- E1: boundary bin sort, take top-`need` ----
    if (need > 0) {
        int cnt = (int)vload(ws + OFF_BINCNT + (b << 10) + bd);
        if (cnt > BUCKET_CAP) cnt = BUCKET_CAP;
        const uint2* bkt = (const uint2*)(ws + OFF_BUCKET) + ((((size_t)b << 10) + bd) << 8);
        for (int t = tid; t < cnt; t += 1024) buf[t] = bkt[t];
        int npad = 1; while (npad < cnt) npad <<= 1;
        for (int t = tid; t < npad; t += 1024) if (t >= cnt) buf[t] = make_uint2(0u, 0xFFFFFFFFu);
        __syncthreads();
        bitonic_sort_shared(buf, npad);
        int sel = (need < cnt) ? need : cnt;
        for (int t = tid; t < sel; t += 1024) {
            int i = (int)buf[t].y;
            int a = i % An, hw = i / An;
            float l = logits[(b * An + a) * HWn + hw];
            cls += bce0(l);
        }
    }
    __syncthreads();

    // ---- E2: positives ----
    {
        int pci = (pc < (uint32_t)POS_CAP) ? (int)pc : POS_CAP;
        const uint2* plist = (const uint2*)(ws + OFF_PLIST) + (size_t)b * POS_CAP;
        int psel = (pci < NPOSMAX) ? pci : NPOSMAX;
        bool use_buf = false;
        if (pci > NPOSMAX) {
            int n = (pci < 2048) ? pci : 2048;
            for (int t = tid; t < n; t += 1024) buf[t] = plist[t];
            int npad = 1; while (npad < n) npad <<= 1;
            for (int t = tid; t < npad; t += 1024) if (t >= n) buf[t] = make_uint2(0u, 0xFFFFFFFFu);
            __syncthreads();
            bitonic_sort_shared(buf, npad);
            use_buf = true;
            psel = (NPOSMAX < n) ? NPOSMAX : n;
        }
        for (int t = tid; t < psel; t += 1024) {
            uint32_t packed = use_buf ? buf[t].y : plist[t].y;
            int i = (int)(packed & 0x1FFFFu);
            int orit = (int)((packed >> 17) & 0x1Fu);
            int a = i % An, hw = i / An;
            float l = logits[(b * An + a) * HWn + hw];
            cls += fmaxf(l, 0.0f) - l + log1pf(expf(-fabsf(l)));   // BCE(l,1)
            float4 avx = ((const float4*)anchors)[b * Nn + i];
            float4 tv = ((const float4*)targets)[b * Mn + orit];
            float aws = avx.z - avx.x + 1.0f, ahs = avx.w - avx.y + 1.0f;
            float axc = avx.x + 0.5f * aws, ayc = avx.y + 0.5f * ahs;
            float tws = tv.z - tv.x + 1.0f, ths = tv.w - tv.y + 1.0f;
            float txc = tv.x + 0.5f * tws, tyc = tv.y + 0.5f * ths;
            float off0 = (txc - axc) / aws;
            float off1 = (tyc - ayc) / ahs;
            float off2 = logf(tws / aws);
            float off3 = logf(ths / ahs);
            float br0 = bregs[(b * 12 + a * 4 + 0) * HWn + hw];
            float br1 = bregs[(b * 12 + a * 4 + 1) * HWn + hw];
            float br2 = bregs[(b * 12 + a * 4 + 2) * HWn + hw];
            float br3 = bregs[(b * 12 + a * 4 + 3) * HWn + hw];
            float d;
            d = fabsf(br0 - off0); reg += (d < BETA) ? 0.5f * d * d / BETA : d - 0.5f * BETA;
            d = fabsf(br1 - off1); reg += (d < BETA) ? 0.5f * d * d / BETA : d - 0.5f * BETA;
            d = fabsf(br2 - off2); reg += (d < BETA) ? 0.5f * d * d / BETA : d - 0.5f * BETA;
            d = fabsf(br3 - off3); reg += (d < BETA) ? 0.5f * d * d / BETA : d - 0.5f * BETA;
        }
    }

    // ---- reductions + cross-image epilogue ----
    fred[tid] = cls;
    __syncthreads();
    for (int s = 512; s > 0; s >>= 1) {
        if (tid < s) fred[tid] += fred[tid + s];
        __syncthreads();
    }
    if (tid == 0 && fred[0] != 0.0f) atomicAdd((float*)&ws[OFF_CLS], fred[0]);
    __syncthreads();
    fred[tid] = reg;
    __syncthreads();
    for (int s = 512; s > 0; s >>= 1) {
        if (tid < s) fred[tid] += fred[tid + s];
        __syncthreads();
    }
    if (tid == 0) {
        if (fred[0] != 0.0f) atomicAdd((float*)&ws[OFF_REG], fred[0]);
        __threadfence();
        uint32_t old = atomicAdd(&ws[OFF_DONE], 1u);
        if (old == Bn - 1) {
            float cls_tot = __uint_as_float(atomicAdd(&ws[OFF_CLS], 0u));
            float reg_tot = __uint_as_float(atomicAdd(&ws[OFF_REG], 0u));
            float cnt = (float)atomicAdd(&ws[OFF_COUNT], 0u);
            out[0] = cls_tot / cnt;
            out[1] = reg_tot / cnt;
        }
    }
}

extern "C" void kernel_launch(void* const* d_in, const int* in_sizes, int n_in,
                              void* d_out, int out_size, void* d_ws, size_t ws_size,
                              hipStream_t stream) {
    const float* anchors = (const float*)d_in[0];   // [B, N, 4]
    const float* logits  = (const float*)d_in[1];   // [B, A, H, W]
    const float* bregs   = (const float*)d_in[2];   // [B, 4A, H, W]
    const float* sizes   = (const float*)d_in[3];   // [B, 2]
    const float* targets = (const float*)d_in[4];   // [B, M, 4]
    float* out = (float*)d_out;
    uint32_t* ws = (uint32_t*)d_ws;

    k0_init<<<dim3((ZERO_WORDS + 255) / 256), dim3(256), 0, stream>>>(ws);
    k1_iou<<<dim3(NBLK, Bn), dim3(256), 0, stream>>>(anchors, targets, sizes, logits, ws);
    k3_final<<<dim3(Bn), dim3(1024), 0, stream>>>(anchors, targets, logits, bregs, ws, out);
}

// Round 5
// 154.584 us; speedup vs baseline: 2.0097x; 1.1732x over previous
//
#include <hip/hip_runtime.h>
#include <stdint.h>

#define Bn 4
#define An 3
#define Hn 168
#define Wn 256
#define Mn 32
#define HWn (Hn*Wn)
#define Nn (HWn*An)          // 129024
#define POS_CAP 8192
#define NPERIM 256
#define NPOSMAX 128
#define FG_THR 0.7f
#define BG_THR 0.3f
#define BETA (1.0f/9.0f)

#define NBLK 126             // blocks per image
#define APT 4                // anchors/thread
#define STRIDE (NBLK * 256)  // 32256
#define NWAVES (NBLK * 4)    // 504 waves per image
#define BUCKET_CAP 256       // per-bin bucket (avg ~78/bin incl. deferred)
#define TSEG_CAP 256         // per-wave deferred segment (max possible = 4*64)

// ---- workspace layout (uint32 word offsets) ----
// [0, ZERO_WORDS) zeroed by k0 each iteration.
#define OFF_POSCNT 0            // Bn
#define OFF_COUNT  8            // 1
#define OFF_CLS    9            // 1 (float bits)
#define OFF_REG    10           // 1 (float bits)
#define OFF_DONE   11           // 1
#define OFF_BINCNT 16           // Bn*1024 = 4096               -> 4112
#define OFF_BINBCE 4112         // Bn*1024 = 4096               -> 8208 (float bits)
#define ZERO_WORDS 8208
#define OFF_PCM    8208         // Bn*NBLK*Mn = 16128           -> 24336 (block colmax)
#define OFF_WPCM   24336        // Bn*NWAVES*32 = 64512         -> 88848 (wave colmax)
#define OFF_TSEGC  88848        // Bn*NWAVES = 2016             -> 90864 (defer counts)
#define OFF_PLIST  90864        // Bn*POS_CAP*2 = 65536         -> 156400
#define OFF_BUCKET 156400       // Bn*1024*BUCKET_CAP*2 = 2097152 -> 2253552
#define OFF_TSEG   2253552      // Bn*NWAVES*TSEG_CAP*4 = 2064384 -> 4317936 (~17.3MB)

// ------------------- threefry2x32 (20 rounds) -------------------
__device__ __forceinline__ uint32_t rotl32(uint32_t v, int n) { return (v << n) | (v >> (32 - n)); }

__device__ __forceinline__ void tf2x32(uint32_t k0, uint32_t k1, uint32_t x0, uint32_t x1,
                                       uint32_t& o0, uint32_t& o1) {
    uint32_t k2 = k0 ^ k1 ^ 0x1BD11BDAu;
    x0 += k0; x1 += k1;
    x0 += x1; x1 = rotl32(x1, 13); x1 ^= x0;
    x0 += x1; x1 = rotl32(x1, 15); x1 ^= x0;
    x0 += x1; x1 = rotl32(x1, 26); x1 ^= x0;
    x0 += x1; x1 = rotl32(x1, 6);  x1 ^= x0;
    x0 += k1; x1 += k2 + 1u;
    x0 += x1; x1 = rotl32(x1, 17); x1 ^= x0;
    x0 += x1; x1 = rotl32(x1, 29); x1 ^= x0;
    x0 += x1; x1 = rotl32(x1, 16); x1 ^= x0;
    x0 += x1; x1 = rotl32(x1, 24); x1 ^= x0;
    x0 += k2; x1 += k0 + 2u;
    x0 += x1; x1 = rotl32(x1, 13); x1 ^= x0;
    x0 += x1; x1 = rotl32(x1, 15); x1 ^= x0;
    x0 += x1; x1 = rotl32(x1, 26); x1 ^= x0;
    x0 += x1; x1 = rotl32(x1, 6);  x1 ^= x0;
    x0 += k0; x1 += k1 + 3u;
    x0 += x1; x1 = rotl32(x1, 17); x1 ^= x0;
    x0 += x1; x1 = rotl32(x1, 29); x1 ^= x0;
    x0 += x1; x1 = rotl32(x1, 16); x1 ^= x0;
    x0 += x1; x1 = rotl32(x1, 24); x1 ^= x0;
    x0 += k1; x1 += k2 + 4u;
    x0 += x1; x1 = rotl32(x1, 13); x1 ^= x0;
    x0 += x1; x1 = rotl32(x1, 15); x1 ^= x0;
    x0 += x1; x1 = rotl32(x1, 26); x1 ^= x0;
    x0 += x1; x1 = rotl32(x1, 6);  x1 ^= x0;
    x0 += k2; x1 += k0 + 5u;
    o0 = x0; o1 = x1;
}

__device__ __forceinline__ uint32_t rng_m23(uint32_t k0, uint32_t k1, uint32_t i) {
    uint32_t o0, o1;
    tf2x32(k0, k1, 0u, i, o0, o1);
    return (o0 ^ o1) >> 9;
}

__device__ __forceinline__ uint32_t vload(const uint32_t* p) {
    return *(const volatile uint32_t*)p;
}

// ------------------- IoU (single definition) ------------
__device__ __forceinline__ float iou_one(float a0, float a1, float a2, float a3,
                                         float t0, float t1, float t2, float t3) {
    float xtl = fmaxf(a0, t0), ytl = fmaxf(a1, t1);
    float xrb = fminf(a2, t2), yrb = fminf(a3, t3);
    float iw = fmaxf(xrb - xtl + 1.0f, 0.0f);
    float ih = fmaxf(yrb - ytl + 1.0f, 0.0f);
    float inter = iw * ih;
    float area1 = (a2 - a0 + 1.0f) * (a3 - a1 + 1.0f);
    float area2 = (t2 - t0 + 1.0f) * (t3 - t1 + 1.0f);
    return inter * __builtin_amdgcn_rcpf(area1 + area2 - inter);
}

__device__ __forceinline__ float bce0(float l) {   // BCE(l, target=0)
    return fmaxf(l, 0.0f) + log1pf(expf(-fabsf(l)));
}

// ------------------- selection order (JAX top_k: larger priority first, tie -> smaller idx)
__device__ __forceinline__ bool sel_less(uint2 a, uint2 b) {
    return (a.x > b.x) || (a.x == b.x && a.y < b.y);
}

__device__ void bitonic_sort_shared(uint2* buf, int n) {   // n = pow2
    for (int k = 2; k <= n; k <<= 1) {
        for (int j = k >> 1; j > 0; j >>= 1) {
            for (int t = (int)threadIdx.x; t < n; t += (int)blockDim.x) {
                int ixj = t ^ j;
                if (ixj > t) {
                    uint2 x = buf[t], y = buf[ixj];
                    bool up = ((t & k) == 0);
                    bool sw = up ? sel_less(y, x) : sel_less(x, y);
                    if (sw) { buf[t] = y; buf[ixj] = x; }
                }
            }
            __syncthreads();
        }
    }
}

// =====================================================================================
// K0: zero control words + bin counters/sums.
// =====================================================================================
__global__ void __launch_bounds__(256) k0_init(uint32_t* __restrict__ ws) {
    int i = blockIdx.x * 256 + (int)threadIdx.x;
    if (i < ZERO_WORDS) ws[i] = 0u;
}

// =====================================================================================
// K1: IoU pass + categorize unambiguous anchors.
//  - FG positives -> PLIST (wave-aggregated ticket; rare)
//  - certain negatives (bg, tie==0) -> bins/buckets + immediate BCE (scattered atomics)
//  - ambiguous (inside, !fg, tie!=0) -> per-wave private segment, ZERO atomics
//  - writes wave colmax (WPCM) and block colmax (PCM) for k2's parallel reduce
// =====================================================================================
__global__ void __launch_bounds__(256) k1_iou(const float* __restrict__ anchors,
                                              const float* __restrict__ targets,
                                              const float* __restrict__ sizes,
                                              const float* __restrict__ logits,
                                              uint32_t* __restrict__ ws) {
    const int b = blockIdx.y, j = blockIdx.x, tid = threadIdx.x;
    const int wid = tid >> 6, lane = tid & 63;
    __shared__ float part[4][Mn];

    uint32_t key0, key1;
    tf2x32(0u, 42u, 0u, (uint32_t)b, key0, key1);   // per-image RNG key (pure fn)

    const int base = j * 256 + tid;
    float4 av[APT];
    #pragma unroll
    for (int k = 0; k < APT; ++k)
        av[k] = ((const float4*)anchors)[b * Nn + base + k * STRIDE];

    float rowmax[APT]; int ori[APT]; uint32_t tie[APT];
    #pragma unroll
    for (int k = 0; k < APT; ++k) { rowmax[k] = -1.0f; ori[k] = 0; tie[k] = 0u; }

    float mycm = 0.0f;   // lane t (t<32) ends holding wave colmax of target t
    #pragma unroll 4
    for (int t = 0; t < Mn; ++t) {
        float4 tv = ((const float4*)targets)[b * Mn + t];
        float io[APT];
        float m0 = 0.0f;
        #pragma unroll
        for (int k = 0; k < APT; ++k) {
            io[k] = iou_one(av[k].x, av[k].y, av[k].z, av[k].w, tv.x, tv.y, tv.z, tv.w);
            if (io[k] > rowmax[k]) { rowmax[k] = io[k]; ori[k] = t; }
            m0 = fmaxf(m0, io[k]);
        }
        #pragma unroll
        for (int o = 32; o > 0; o >>= 1) m0 = fmaxf(m0, __shfl_xor(m0, o, 64));
        if (lane == t) mycm = m0;
        #pragma unroll
        for (int k = 0; k < APT; ++k)
            tie[k] |= (io[k] == m0) ? (1u << t) : 0u;
    }

    // wave colmax -> global; block colmax via LDS -> global
    const int wimg = j * 4 + wid;
    if (lane < Mn) {
        ws[OFF_WPCM + ((size_t)b * NWAVES + wimg) * 32 + lane] = __float_as_uint(mycm);
        part[wid][lane] = mycm;
    }
    __syncthreads();
    if (tid < Mn) {
        float v = fmaxf(fmaxf(part[0][tid], part[1][tid]),
                        fmaxf(part[2][tid], part[3][tid]));
        ws[OFF_PCM + ((size_t)b * NBLK + j) * Mn + tid] = __float_as_uint(v);
    }

    const float sh = sizes[b * 2 + 0], sw = sizes[b * 2 + 1];
    unsigned long long lt_mask = (lane == 63) ? 0x7FFFFFFFFFFFFFFFull
                                              : ((1ull << lane) - 1ull);
    uint4* tseg = (uint4*)(ws + OFF_TSEG) + ((size_t)b * NWAVES + wimg) * TSEG_CAP;
    uint32_t wcnt = 0;   // wave-uniform running defer count (ballot popc)
    #pragma unroll
    for (int k = 0; k < APT; ++k) {
        const int i = base + k * STRIDE;
        bool inside = (av[k].x >= 0.0f) && (av[k].y >= 0.0f) &&
                      (av[k].z <= sw - 1.0f) && (av[k].w <= sh - 1.0f);
        bool fg = rowmax[k] >= FG_THR;
        bool bg = rowmax[k] < BG_THR;
        bool posn   = inside && fg;
        bool defern = inside && !fg && (tie[k] != 0u);
        bool negn   = inside && bg && (tie[k] == 0u);
        uint32_t m = rng_m23(key0, key1, (uint32_t)i);

        unsigned long long pmask = __ballot(posn);
        if (pmask) {
            int leader = __ffsll((long long)pmask) - 1;
            uint32_t bb = 0;
            if (lane == leader) bb = atomicAdd(&ws[OFF_POSCNT + b], (uint32_t)__popcll(pmask));
            bb = __shfl(bb, leader, 64);
            if (posn) {
                uint32_t p = bb + (uint32_t)__popcll(pmask & lt_mask);
                if (p < POS_CAP)
                    ((uint2*)(ws + OFF_PLIST))[(size_t)b * POS_CAP + p] =
                        make_uint2(m, (uint32_t)i | ((uint32_t)ori[k] << 17));
            }
        }
        unsigned long long dmask = __ballot(defern);
        if (defern) {
            uint32_t slot = wcnt + (uint32_t)__popcll(dmask & lt_mask);
            tseg[slot] = make_uint4(tie[k], m,
                                    (uint32_t)i | ((uint32_t)ori[k] << 17) | (bg ? (1u << 22) : 0u),
                                    0u);
        }
        wcnt += (uint32_t)__popcll(dmask);
        if (negn) {
            int bin = (int)(m >> 13);
            uint32_t slot = atomicAdd(&ws[OFF_BINCNT + (b << 10) + bin], 1u);
            if (slot < BUCKET_CAP)
                ((uint2*)(ws + OFF_BUCKET))[((((size_t)b << 10) + bin) << 8) + slot] =
                    make_uint2(m, (uint32_t)i);
            int a = i % An, hw = i / An;
            float l = logits[(b * An + a) * HWn + hw];
            atomicAdd((float*)&ws[OFF_BINBCE + (b << 10) + bin], bce0(l));
        }
    }
    if (lane == 0) ws[OFF_TSEGC + b * NWAVES + wimg] = wcnt;
}

// =====================================================================================
// K2: resolve deferred ties on the FULL grid (126x4 blocks). Each block:
//  - redundantly reduces PCM (16KB/image, parallel across blocks: R2-proven pattern)
//  - eqmask for its own 4 waves; resolves its own ~64 deferred entries
//  (R4 lesson: doing this in a 4-block kernel = 64us of latency-bound serial fetch.)
// =====================================================================================
__global__ void __launch_bounds__(256) k2_resolve(const float* __restrict__ logits,
                                                  uint32_t* __restrict__ ws) {
    const int b = blockIdx.y, j = blockIdx.x, tid = threadIdx.x;
    const int lane = tid & 63;
    __shared__ float redf[256];
    __shared__ uint32_t cmb[Mn];
    __shared__ uint32_t eqs[4];
    __shared__ uint32_t cnts[4];

    // global colmax from per-block PCM (exact: max assoc/comm)
    {
        int t = tid & 31, sub = tid >> 5;
        float acc = 0.0f;
        for (int jj = sub; jj < NBLK; jj += 8)
            acc = fmaxf(acc, __uint_as_float(ws[OFF_PCM + ((size_t)b * NBLK + jj) * Mn + t]));
        redf[tid] = acc;
        __syncthreads();
        if (sub == 0) {
            #pragma unroll
            for (int q = 1; q < 8; ++q) acc = fmaxf(acc, redf[t + 32 * q]);
            cmb[t] = __float_as_uint(acc);
        }
    }
    if (tid < 4) {
        eqs[tid] = 0u;
        cnts[tid] = ws[OFF_TSEGC + b * NWAVES + j * 4 + tid];
    }
    __syncthreads();
    // eqmask for this block's 4 k1-waves
    if (tid < 128) {
        int lw = tid >> 5, t2 = tid & 31;
        uint32_t wv = ws[OFF_WPCM + ((size_t)b * NWAVES + j * 4 + lw) * 32 + t2];
        if (wv == cmb[t2]) atomicOr(&eqs[lw], 1u << t2);
    }
    __syncthreads();

    const uint32_t c0 = cnts[0], c1 = cnts[1], c2 = cnts[2], c3 = cnts[3];
    const int total = (int)(c0 + c1 + c2 + c3);
    unsigned long long lt_mask = (lane == 63) ? 0x7FFFFFFFFFFFFFFFull
                                              : ((1ull << lane) - 1ull);
    for (int f = tid; f < total; f += 256) {
        int lw, o;
        if ((uint32_t)f < c0)                { lw = 0; o = f; }
        else if ((uint32_t)f < c0 + c1)      { lw = 1; o = f - (int)c0; }
        else if ((uint32_t)f < c0 + c1 + c2) { lw = 2; o = f - (int)(c0 + c1); }
        else                                 { lw = 3; o = f - (int)(c0 + c1 + c2); }
        uint4 e = ((const uint4*)(ws + OFF_TSEG))
                      [((size_t)b * NWAVES + j * 4 + lw) * TSEG_CAP + o];
        int i = (int)(e.z & 0x1FFFFu);
        bool restored = (e.x & eqs[lw]) != 0u;

        unsigned long long rmask = __ballot(restored);
        if (rmask) {
            int leader = __ffsll((long long)rmask) - 1;
            uint32_t bb = 0;
            if (lane == leader) bb = atomicAdd(&ws[OFF_POSCNT + b], (uint32_t)__popcll(rmask));
            bb = __shfl(bb, leader, 64);
            if (restored) {
                uint32_t p = bb + (uint32_t)__popcll(rmask & lt_mask);
                if (p < POS_CAP)
                    ((uint2*)(ws + OFF_PLIST))[(size_t)b * POS_CAP + p] =
                        make_uint2(e.y, e.z & 0x3FFFFFu);   // strip bg bit
            }
        }
        if (!restored && (e.z & (1u << 22))) {   // bg, not restored -> negative
            uint32_t m = e.y;
            int bin = (int)(m >> 13);
            uint32_t slot = atomicAdd(&ws[OFF_BINCNT + (b << 10) + bin], 1u);
            if (slot < BUCKET_CAP)
                ((uint2*)(ws + OFF_BUCKET))[((((size_t)b << 10) + bin) << 8) + slot] =
                    make_uint2(m, (uint32_t)i);
            int a = i % An, hw = i / An;
            float l = logits[(b * An + a) * HWn + hw];
            atomicAdd((float*)&ws[OFF_BINBCE + (b << 10) + bin], bce0(l));
        }
        // mid, not restored -> dropped
    }
}

// =====================================================================================
// K3: per-image finalize, 1024 threads (one block per image). Small fetches only:
//  bin suffix scan (1:1 threads<->bins) -> boundary + included-bin BCE;
//  boundary-bin sort; positives sort/epilogue; cross-image output.
// =====================================================================================
__global__ void __launch_bounds__(1024) k3_final(const float* __restrict__ anchors,
                                                 const float* __restrict__ targets,
                                                 const float* __restrict__ logits,
                                                 const float* __restrict__ bregs,
                                                 uint32_t* __restrict__ ws,
                                                 float* __restrict__ out) {
    const int b = blockIdx.x, tid = threadIdx.x;
    __shared__ uint32_t csum[1024];
    __shared__ uint2 buf[2048];
    __shared__ float fred[1024];
    __shared__ int s_bd, s_need;
    float cls = 0.0f, reg = 0.0f;

    // ---- suffix scan of bin counts (bin == tid) ----
    csum[tid] = vload(ws + OFF_BINCNT + (b << 10) + tid);
    __syncthreads();
    for (int off = 1; off < 1024; off <<= 1) {
        uint32_t v = csum[tid];
        uint32_t add = (tid + off < 1024) ? csum[tid + off] : 0u;
        __syncthreads();
        csum[tid] = v + add;
        __syncthreads();
    }
    uint32_t pc = vload(ws + OFF_POSCNT + b);    // final (incl. restored)
    int num_pos = (pc < (uint32_t)NPOSMAX) ? (int)pc : NPOSMAX;
    int k_neg = NPERIM - num_pos;
    uint32_t total = csum[0];
    if (tid == 0 && (int)total < k_neg) { s_bd = -1; s_need = 0; }
    {
        uint32_t inclv = csum[tid];
        uint32_t nxt = (tid < 1023) ? csum[tid + 1] : 0u;
        if ((int)total >= k_neg && (int)inclv >= k_neg && (int)nxt < k_neg) {
            s_bd = tid; s_need = k_neg - (int)nxt;
        }
    }
    if (tid == 0) {
        int sel_negs = ((int)total < k_neg) ? (int)total : k_neg;
        atomicAdd(&ws[OFF_COUNT], (uint32_t)(num_pos + sel_negs));
    }
    __syncthreads();
    const int bd = s_bd, need = s_need;
    if ((int)tid > bd)
        cls += __uint_as_float(vload(ws + OFF_BINBCE + (b << 10) + tid));
    __syncthreads();

    // ---- boundary bin: sort, take top-`need` ----
    if (need > 0) {
        int cnt = (int)vload(ws + OFF_BINCNT + (b << 10) + bd);
        if (cnt > BUCKET_CAP) cnt = BUCKET_CAP;
        const uint2* bkt = (const uint2*)(ws + OFF_BUCKET) + ((((size_t)b << 10) + bd) << 8);
        for (int t = tid; t < cnt; t += 1024) buf[t] = bkt[t];
        int npad = 1; while (npad < cnt) npad <<= 1;
        for (int t = tid; t < npad; t += 1024) if (t >= cnt) buf[t] = make_uint2(0u, 0xFFFFFFFFu);
        __syncthreads();
        bitonic_sort_shared(buf, npad);
        int sel = (need < cnt) ? need : cnt;
        for (int t = tid; t < sel; t += 1024) {
            int i = (int)buf[t].y;
            int a = i % An, hw = i / An;
            float l = logits[(b * An + a) * HWn + hw];
            cls += bce0(l);
        }
    }
    __syncthreads();

    // ---- positives ----
    {
        int pci = (pc < (uint32_t)POS_CAP) ? (int)pc : POS_CAP;
        const uint2* plist = (const uint2*)(ws + OFF_PLIST) + (size_t)b * POS_CAP;
        int psel = (pci < NPOSMAX) ? pci : NPOSMAX;
        bool use_buf = false;
        if (pci > NPOSMAX) {
            int n = (pci < 2048) ? pci : 2048;
            for (int t = tid; t < n; t += 1024) buf[t] = plist[t];
            int npad = 1; while (npad < n) npad <<= 1;
            for (int t = tid; t < npad; t += 1024) if (t >= n) buf[t] = make_uint2(0u, 0xFFFFFFFFu);
            __syncthreads();
            bitonic_sort_shared(buf, npad);
            use_buf = true;
            psel = (NPOSMAX < n) ? NPOSMAX : n;
        }
        for (int t = tid; t < psel; t += 1024) {
            uint32_t packed = use_buf ? buf[t].y : plist[t].y;
            int i = (int)(packed & 0x1FFFFu);
            int orit = (int)((packed >> 17) & 0x1Fu);
            int a = i % An, hw = i / An;
            float l = logits[(b * An + a) * HWn + hw];
            cls += fmaxf(l, 0.0f) - l + log1pf(expf(-fabsf(l)));   // BCE(l,1)
            float4 avx = ((const float4*)anchors)[b * Nn + i];
            float4 tv = ((const float4*)targets)[b * Mn + orit];
            float aws = avx.z - avx.x + 1.0f, ahs = avx.w - avx.y + 1.0f;
            float axc = avx.x + 0.5f * aws, ayc = avx.y + 0.5f * ahs;
            float tws = tv.z - tv.x + 1.0f, ths = tv.w - tv.y + 1.0f;
            float txc = tv.x + 0.5f * tws, tyc = tv.y + 0.5f * ths;
            float off0 = (txc - axc) / aws;
            float off1 = (tyc - ayc) / ahs;
            float off2 = logf(tws / aws);
            float off3 = logf(ths / ahs);
            float br0 = bregs[(b * 12 + a * 4 + 0) * HWn + hw];
            float br1 = bregs[(b * 12 + a * 4 + 1) * HWn + hw];
            float br2 = bregs[(b * 12 + a * 4 + 2) * HWn + hw];
            float br3 = bregs[(b * 12 + a * 4 + 3) * HWn + hw];
            float d;
            d = fabsf(br0 - off0); reg += (d < BETA) ? 0.5f * d * d / BETA : d - 0.5f * BETA;
            d = fabsf(br1 - off1); reg += (d < BETA) ? 0.5f * d * d / BETA : d - 0.5f * BETA;
            d = fabsf(br2 - off2); reg += (d < BETA) ? 0.5f * d * d / BETA : d - 0.5f * BETA;
            d = fabsf(br3 - off3); reg += (d < BETA) ? 0.5f * d * d / BETA : d - 0.5f * BETA;
        }
    }

    // ---- reductions + cross-image epilogue ----
    fred[tid] = cls;
    __syncthreads();
    for (int s = 512; s > 0; s >>= 1) {
        if (tid < s) fred[tid] += fred[tid + s];
        __syncthreads();
    }
    if (tid == 0 && fred[0] != 0.0f) atomicAdd((float*)&ws[OFF_CLS], fred[0]);
    __syncthreads();
    fred[tid] = reg;
    __syncthreads();
    for (int s = 512; s > 0; s >>= 1) {
        if (tid < s) fred[tid] += fred[tid + s];
        __syncthreads();
    }
    if (tid == 0) {
        if (fred[0] != 0.0f) atomicAdd((float*)&ws[OFF_REG], fred[0]);
        __threadfence();
        uint32_t old = atomicAdd(&ws[OFF_DONE], 1u);
        if (old == Bn - 1) {
            float cls_tot = __uint_as_float(atomicAdd(&ws[OFF_CLS], 0u));
            float reg_tot = __uint_as_float(atomicAdd(&ws[OFF_REG], 0u));
            float cnt = (float)atomicAdd(&ws[OFF_COUNT], 0u);
            out[0] = cls_tot / cnt;
            out[1] = reg_tot / cnt;
        }
    }
}

extern "C" void kernel_launch(void* const* d_in, const int* in_sizes, int n_in,
                              void* d_out, int out_size, void* d_ws, size_t ws_size,
                              hipStream_t stream) {
    const float* anchors = (const float*)d_in[0];   // [B, N, 4]
    const float* logits  = (const float*)d_in[1];   // [B, A, H, W]
    const float* bregs   = (const float*)d_in[2];   // [B, 4A, H, W]
    const float* sizes   = (const float*)d_in[3];   // [B, 2]
    const float* targets = (const float*)d_in[4];   // [B, M, 4]
    float* out = (float*)d_out;
    uint32_t* ws = (uint32_t*)d_ws;

    k0_init<<<dim3((ZERO_WORDS + 255) / 256), dim3(256), 0, stream>>>(ws);
    k1_iou<<<dim3(NBLK, Bn), dim3(256), 0, stream>>>(anchors, targets, sizes, logits, ws);
    k2_resolve<<<dim3(NBLK, Bn), dim3(256), 0, stream>>>(logits, ws);
    k3_final<<<dim3(Bn), dim3(1024), 0, stream>>>(anchors, targets, logits, bregs, ws, out);
}